// Round 13
// baseline (254.650 us; speedup 1.0000x reference)
//
#include <hip/hip_runtime.h>
#include <math.h>

#define EPSF 1e-12f
#define LOG2E 1.44269504f

// ---- DPP-based reductions (no DS pipe, no lane-addr calc) ----
template <int CTRL>
__device__ __forceinline__ float dppadd(float x) {
    union { float f; int i; } u, r;
    u.f = x;
    r.i = __builtin_amdgcn_update_dpp(0, u.i, CTRL, 0xF, 0xF, false);
    return x + r.f;
}
__device__ __forceinline__ float red16(float v) {
    v = dppadd<0xB1>(v); v = dppadd<0x4E>(v);
    v = dppadd<0x141>(v); v = dppadd<0x140>(v);
    return v;  // all 16 lanes hold the total
}
__device__ __forceinline__ float red8(float v) {
    v = dppadd<0xB1>(v); v = dppadd<0x4E>(v); v = dppadd<0x141>(v);
    return v;  // all 8 lanes hold the total
}
__device__ __forceinline__ float xor8add(float v) {  // combine 8-halves in 16
    return dppadd<0x128>(v);
}

// tanh(x) = 1 - 2/(e^{2x}+1) with HW exp2/rcp (exact at +/-inf limits)
__device__ __forceinline__ float fast_tanh(float x) {
    float E = __builtin_amdgcn_exp2f(x * (2.0f * LOG2E));
    return 1.0f - 2.0f * __builtin_amdgcn_rcpf(E + 1.0f);
}

// 1/max(sqrt(x), 1e-12) == rsq(max(x, 1e-24)) (monotone transform, exact)
__device__ __forceinline__ float inv_norm(float x) {
    return __builtin_amdgcn_rsqf(fmaxf(x, 1e-24f));
}

__device__ __forceinline__ float leaky(float x) {
    return x > 0.0f ? x : 0.01f * x;
}

// ---- prep, 5 segments:
// [0,N16):          dn[n] = {ent.entT dot, |ent|^2} per node (16 lanes/node)
// [N16,N16+E):      degree count
// [.., +N16):       hrp[n][r] = ent[n].relT[r]  (one lane per (n,r))
// [.., +16):        rp2[r] = |relT[r]|^2
// [.., +1280):      transposed-weight float4 blocks
__global__ __launch_bounds__(256) void prep(
    const float* __restrict__ ent, const float* __restrict__ entT,
    float2* __restrict__ dn, const int* __restrict__ dst,
    int* __restrict__ deg, int N16, int E,
    const float* __restrict__ relT, float* __restrict__ hrp,
    float* __restrict__ rp2,
    const float* __restrict__ W10, const float* __restrict__ W20,
    const float* __restrict__ W11, const float* __restrict__ W21,
    float4* __restrict__ wt) {
    int gid = blockIdx.x * 256 + threadIdx.x;
    if (gid < N16) {   // 16-lane rows never straddle (N16 mult of 16)
        int v = gid >> 4, lane = gid & 15;
        const float4 a = *(const float4*)(ent  + (size_t)v * 64 + lane * 4);
        const float4 b = *(const float4*)(entT + (size_t)v * 64 + lane * 4);
        float d  = red16(a.x*b.x + a.y*b.y + a.z*b.z + a.w*b.w);
        float n2 = red16(a.x*a.x + a.y*a.y + a.z*a.z + a.w*a.w);
        if (lane == 0) dn[v] = make_float2(d, n2);
    } else if (gid < N16 + E) {
        int e = gid - N16;
        atomicAdd(&deg[dst[e]], 1);
    } else if (gid < N16 + E + N16) {
        int idx = gid - N16 - E;
        int n = idx >> 4, r = idx & 15;
        const float4* e4 = (const float4*)(ent + (size_t)n * 64);
        const float4* w4 = (const float4*)(relT + r * 64);
        float acc = 0.0f;
        #pragma unroll
        for (int k = 0; k < 16; ++k) {
            float4 a = e4[k], b = w4[k];
            acc += a.x*b.x + a.y*b.y + a.z*b.z + a.w*b.w;
        }
        hrp[n * 16 + r] = acc;
    } else if (gid < N16 + E + N16 + 16) {
        int r = gid - N16 - E - N16;
        const float4* w4 = (const float4*)(relT + r * 64);
        float acc = 0.0f;
        #pragma unroll
        for (int k = 0; k < 16; ++k) {
            float4 b = w4[k];
            acc += b.x*b.x + b.y*b.y + b.z*b.z + b.w*b.w;
        }
        rp2[r] = acc;
    } else {
        int w = gid - N16 - E - N16 - 16;  // 0..1279
        if (w < 512) {
            int dd = w >> 5, j = w & 31, d4 = dd * 4;
            wt[w] = make_float4(W10[(d4+0)*32+j], W10[(d4+1)*32+j],
                                W10[(d4+2)*32+j], W10[(d4+3)*32+j]);
        } else if (w < 1024) {
            int u = w - 512, dd = u >> 5, j = u & 31, d4 = dd * 4;
            wt[w] = make_float4(W20[(d4+0)*32+j], W20[(d4+1)*32+j],
                                W20[(d4+2)*32+j], W20[(d4+3)*32+j]);
        } else if (w < 1152) {
            int u = w - 1024, dd = u >> 4, j = u & 15, d4 = dd * 4;
            wt[w] = make_float4(W11[(d4+0)*16+j], W11[(d4+1)*16+j],
                                W11[(d4+2)*16+j], W11[(d4+3)*16+j]);
        } else if (w < 1280) {
            int u = w - 1152, dd = u >> 4, j = u & 15, d4 = dd * 4;
            wt[w] = make_float4(W21[(d4+0)*16+j], W21[(d4+1)*16+j],
                                W21[(d4+2)*16+j], W21[(d4+3)*16+j]);
        }
    }
}

// ---------------- CSR scan kernels ----------------

__global__ __launch_bounds__(256) void scan_reduce(
    const int* __restrict__ deg, int* __restrict__ part, int N) {
    __shared__ int sh[256];
    int t = threadIdx.x, i = blockIdx.x * 256 + t;
    sh[t] = (i < N) ? deg[i] : 0;
    __syncthreads();
    for (int off = 128; off > 0; off >>= 1) {
        if (t < off) sh[t] += sh[t + off];
        __syncthreads();
    }
    if (t == 0) part[blockIdx.x] = sh[0];
}

__global__ __launch_bounds__(1024) void scan_part(int* __restrict__ part, int nb) {
    __shared__ int sh[1024];
    int t = threadIdx.x;
    int x = (t < nb) ? part[t] : 0;
    sh[t] = x;
    __syncthreads();
    for (int off = 1; off < 1024; off <<= 1) {
        int y = (t >= off) ? sh[t - off] : 0;
        __syncthreads();
        sh[t] += y;
        __syncthreads();
    }
    if (t < nb) part[t] = sh[t] - x;  // exclusive
}

__global__ __launch_bounds__(256) void scan_write(
    int* __restrict__ rowptr, const int* __restrict__ part, int N) {
    __shared__ int sh[256];
    int t = threadIdx.x, i = blockIdx.x * 256 + t;
    int x = (i < N) ? rowptr[i] : 0;
    sh[t] = x;
    __syncthreads();
    for (int off = 1; off < 256; off <<= 1) {
        int y = (t >= off) ? sh[t - off] : 0;
        __syncthreads();
        sh[t] += y;
        __syncthreads();
    }
    if (i < N) rowptr[i] = part[blockIdx.x] + sh[t] - x;  // exclusive scan
}

// After this, rowptr[v] = end(v); start(v) = (v ? rowptr[v-1] : 0).
// Slot payload int4: { src|ety<<20, dot[src], it, ih } — the two edge
// normalizers are computed HERE from precomputed quadratic-form terms.
__global__ __launch_bounds__(256) void scatter_edges(
    const int* __restrict__ src, const int* __restrict__ dst,
    const int* __restrict__ ety, const float2* __restrict__ dn,
    const float* __restrict__ hrp, const float* __restrict__ rp2,
    int* __restrict__ rowptr, int4* __restrict__ spk4, int E) {
    int e = blockIdx.x * 256 + threadIdx.x;
    if (e < E) {
        int sv = src[e], dv = dst[e], rv = ety[e];
        float2 dns = dn[sv], dnd = dn[dv];
        float hs = hrp[sv * 16 + rv], hd = hrp[dv * 16 + rv];
        float r2 = rp2[rv];
        float sdt = dns.x, dh = dnd.x;
        // |te + sdt*rp|^2 and |he + dh*rp|^2 via quadratic expansion
        float sst = dns.y + 2.0f * sdt * hs + sdt * sdt * r2;
        float ssh = dnd.y + 2.0f * dh  * hd + dh  * dh  * r2;
        float it = inv_norm(sst);
        float ih = inv_norm(ssh);
        int slot = atomicAdd(&rowptr[dv], 1);
        spk4[slot] = make_int4(sv | (rv << 20), __float_as_int(sdt),
                               __float_as_int(it), __float_as_int(ih));
    }
}

// ------------- fused layer-0: att + softmax + message + bi-layer GEMV -------
// 32 lanes per dst node (8 nodes / 256-thread block): two 16-lane halves each
// walk half the node's edge list with a dual-edge pipeline + next-pair
// prefetch. Normalizers it/ih arrive precomputed in the payload — no
// per-edge norm reductions remain; only the attention dot red16.
__global__ __launch_bounds__(256) void fused_l0(
    const int* __restrict__ rowptr, const int4* __restrict__ spk4,
    const float* __restrict__ ent, const float2* __restrict__ dn,
    const float* __restrict__ relE, const float* __restrict__ relT,
    const float4* __restrict__ wt,
    const float* __restrict__ b1, const float* __restrict__ b2,
    float* __restrict__ exatt, float* __restrict__ sinv,
    float* __restrict__ node1raw, float* __restrict__ out, int N) {
    __shared__ float  al[8][64];
    __shared__ float  bl[8][64];
    __shared__ float  rT[16][64];    // rel tables (16 rels x 64)
    __shared__ float  rE[16][64];
    __shared__ float4 WtA[512];      // W1^T (pre-transposed in prep)
    __shared__ float4 WtB[512];
    int t = threadIdx.x;

    {   // stage rel tables + weights (pure coalesced float4 copies)
        int r = t >> 4, c = (t & 15) * 4;
        *(float4*)&rT[r][c] = *(const float4*)(relT + r * 64 + c);
        *(float4*)&rE[r][c] = *(const float4*)(relE + r * 64 + c);
        WtA[t]       = wt[t];
        WtA[t + 256] = wt[t + 256];
        WtB[t]       = wt[512 + t];
        WtB[t + 256] = wt[768 + t];
    }
    __syncthreads();  // the only block barrier

    int nv = t >> 5, half = (t >> 4) & 1, lane = t & 15;
    int v = blockIdx.x * 8 + nv;
    if (v >= N) return;

    int s = v ? rowptr[v - 1] : 0;
    int epos = rowptr[v];
    int deg = epos - s;
    int mid = s + ((deg + 1) >> 1);
    int hs   = half ? mid  : s;
    int hend = half ? epos : mid;

    const float4 he = *(const float4*)(ent + (size_t)v * 64 + lane * 4);
    float dh = dn[v].x;

    float4 macc = {0.f, 0.f, 0.f, 0.f};
    float sumex = 0.0f;

    for (int base = hs; base < hend; base += 16) {
        int rem = hend - base;
        int cnt = rem < 16 ? rem : 16;
        int4 ms = spk4[base + (lane < rem ? lane : rem - 1)];  // coalesced 16B
        float myex = 0.0f;

        int e1i = cnt > 1 ? 1 : 0;
        int   pk0 = __shfl(ms.x, 0, 16);
        int   pk1 = __shfl(ms.x, e1i, 16);
        float sd0 = __int_as_float(__shfl(ms.y, 0, 16));
        float sd1 = __int_as_float(__shfl(ms.y, e1i, 16));
        float it0 = __int_as_float(__shfl(ms.z, 0, 16));
        float it1 = __int_as_float(__shfl(ms.z, e1i, 16));
        float ih0 = __int_as_float(__shfl(ms.w, 0, 16));
        float ih1 = __int_as_float(__shfl(ms.w, e1i, 16));
        float4 te0 = *(const float4*)(ent + (size_t)(pk0 & 0xFFFFF) * 64 + lane * 4);
        float4 te1 = *(const float4*)(ent + (size_t)(pk1 & 0xFFFFF) * 64 + lane * 4);

        for (int k = 0; k < cnt; k += 2) {
            float4 ta = te0, tb = te1;
            float  sa = sd0, sb = sd1;
            float ita = it0, itb = it1, iha = ih0, ihb = ih1;
            int rva = (pk0 >> 20) & 15;
            int rvb = (pk1 >> 20) & 15;
            bool hasb = (k + 1) < cnt;

            if (k + 2 < cnt) {  // prefetch next pair while computing this one
                int i2 = k + 2, i3 = (k + 3 < cnt) ? (k + 3) : (k + 2);
                pk0 = __shfl(ms.x, i2, 16);
                pk1 = __shfl(ms.x, i3, 16);
                sd0 = __int_as_float(__shfl(ms.y, i2, 16));
                sd1 = __int_as_float(__shfl(ms.y, i3, 16));
                it0 = __int_as_float(__shfl(ms.z, i2, 16));
                it1 = __int_as_float(__shfl(ms.z, i3, 16));
                ih0 = __int_as_float(__shfl(ms.w, i2, 16));
                ih1 = __int_as_float(__shfl(ms.w, i3, 16));
                te0 = *(const float4*)(ent + (size_t)(pk0 & 0xFFFFF) * 64 + lane * 4);
                te1 = *(const float4*)(ent + (size_t)(pk1 & 0xFFFFF) * 64 + lane * 4);
            }

            const float4 rpa = *(const float4*)&rT[rva][lane * 4];
            const float4 rea = *(const float4*)&rE[rva][lane * 4];
            const float4 rpb = *(const float4*)&rT[rvb][lane * 4];
            const float4 reb = *(const float4*)&rE[rvb][lane * 4];

            float4 mta, mha, mtb, mhb;
            mta.x = ta.x + sa * rpa.x; mta.y = ta.y + sa * rpa.y;
            mta.z = ta.z + sa * rpa.z; mta.w = ta.w + sa * rpa.w;
            mha.x = he.x + dh * rpa.x; mha.y = he.y + dh * rpa.y;
            mha.z = he.z + dh * rpa.z; mha.w = he.w + dh * rpa.w;
            mtb.x = tb.x + sb * rpb.x; mtb.y = tb.y + sb * rpb.y;
            mtb.z = tb.z + sb * rpb.z; mtb.w = tb.w + sb * rpb.w;
            mhb.x = he.x + dh * rpb.x; mhb.y = he.y + dh * rpb.y;
            mhb.z = he.z + dh * rpb.z; mhb.w = he.w + dh * rpb.w;

            float txa = fast_tanh(mha.x * iha + rea.x);
            float tya = fast_tanh(mha.y * iha + rea.y);
            float tza = fast_tanh(mha.z * iha + rea.z);
            float twa = fast_tanh(mha.w * iha + rea.w);
            float txb = fast_tanh(mhb.x * ihb + reb.x);
            float tyb = fast_tanh(mhb.y * ihb + reb.y);
            float tzb = fast_tanh(mhb.z * ihb + reb.z);
            float twb = fast_tanh(mhb.w * ihb + reb.w);

            float atta = ita * red16(mta.x*txa + mta.y*tya + mta.z*tza + mta.w*twa);
            float attb = itb * red16(mtb.x*txb + mtb.y*tyb + mtb.z*tzb + mtb.w*twb);

            // softmax shift-invariant; |att| <= 8 so exp is safe without max-sub
            float exa  = __builtin_amdgcn_exp2f(atta * LOG2E);
            float exbR = __builtin_amdgcn_exp2f(attb * LOG2E);
            float exb  = hasb ? exbR : 0.0f;

            // lane k captures its edge's raw ex; stored coalesced per chunk
            myex = (lane == k) ? exa : myex;
            myex = (lane == k + 1) ? exbR : myex;

            sumex += exa + exb;
            macc.x += exa * ta.x + exb * tb.x;
            macc.y += exa * ta.y + exb * tb.y;
            macc.z += exa * ta.z + exb * tb.z;
            macc.w += exa * ta.w + exb * tb.w;
        }
        if (lane < cnt) exatt[base + lane] = myex;
    }

    // combine the two halves of this node (width-32 xor-by-16)
    sumex  += __shfl_xor(sumex,  16, 32);
    macc.x += __shfl_xor(macc.x, 16, 32);
    macc.y += __shfl_xor(macc.y, 16, 32);
    macc.z += __shfl_xor(macc.z, 16, 32);
    macc.w += __shfl_xor(macc.w, 16, 32);

    float inv = 1.0f / fmaxf(sumex, EPSF);
    if ((t & 31) == 0) sinv[v] = inv;
    macc.x *= inv; macc.y *= inv; macc.z *= inv; macc.w *= inv;

    if (!half) {
        // out cols 0..63 = ent_embed
        *(float4*)(out + (size_t)v * 112 + lane * 4) = he;
        float4 av, bv;
        av.x = he.x + macc.x; av.y = he.y + macc.y;
        av.z = he.z + macc.z; av.w = he.w + macc.w;
        bv.x = he.x * macc.x; bv.y = he.y * macc.y;
        bv.z = he.z * macc.z; bv.w = he.w * macc.w;
        *(float4*)&al[nv][lane * 4] = av;
        *(float4*)&bl[nv][lane * 4] = bv;
    }
    // no __syncthreads: writers and readers are the same wave (program order)

    int j = t & 31;
    float acc1 = b1[j], acc2 = b2[j];
    #pragma unroll
    for (int dd = 0; dd < 16; ++dd) {
        float4 a4 = *(const float4*)&al[nv][dd * 4];   // LDS broadcast read
        float4 b4 = *(const float4*)&bl[nv][dd * 4];
        float4 wa = WtA[dd * 32 + j];                  // coalesced b128
        float4 wb = WtB[dd * 32 + j];
        acc1 += a4.x*wa.x + a4.y*wa.y + a4.z*wa.z + a4.w*wa.w;
        acc2 += b4.x*wb.x + b4.y*wb.y + b4.z*wb.z + b4.w*wb.w;
    }
    node1raw[(size_t)v * 32 + j] = leaky(acc1) + leaky(acc2);
}

// ------------- fused layer-1: message gather + bi-layer GEMV + norms --------
// 16 lanes per node (16 nodes / block): two 8-lane halves, dual-edge pipeline.
__global__ __launch_bounds__(256) void fused_l1(
    const int* __restrict__ rowptr, const int4* __restrict__ spk4,
    const float* __restrict__ exatt, const float* __restrict__ sinv,
    const float* __restrict__ node1raw, const float4* __restrict__ wt,
    const float* __restrict__ b1, const float* __restrict__ b2,
    float* __restrict__ out, int N) {
    __shared__ float  A[16][32];
    __shared__ float  B[16][32];
    __shared__ float4 WtC[128];  // W1^T (pre-transposed in prep)
    __shared__ float4 WtD[128];
    int t = threadIdx.x;

    {   // stage weights (pure coalesced float4 copies)
        if (t < 128) WtC[t] = wt[1024 + t];
        else WtD[t - 128] = wt[1024 + t];
    }
    __syncthreads();

    int nv = t >> 4, half = (t >> 3) & 1, lane = t & 7;
    int v = blockIdx.x * 16 + nv;
    if (v >= N) return;

    int s = v ? rowptr[v - 1] : 0;
    int epos = rowptr[v];
    int deg = epos - s;
    int mid = s + ((deg + 1) >> 1);
    int hs   = half ? mid  : s;
    int hend = half ? epos : mid;

    float4 n = *(const float4*)(node1raw + (size_t)v * 32 + lane * 4);
    float4 acc = {0.f, 0.f, 0.f, 0.f};

    for (int base = hs; base < hend; base += 8) {
        int rem = hend - base;
        int cnt = rem < 8 ? rem : 8;
        int idx = base + (lane < rem ? lane : rem - 1);
        int   mypk = spk4[idx].x;
        float myex = exatt[idx];

        int pk0 = __shfl(mypk, 0, 8);
        int pk1 = __shfl(mypk, cnt > 1 ? 1 : 0, 8);
        float4 x0 = *(const float4*)(node1raw + (size_t)(pk0 & 0xFFFFF) * 32 + lane * 4);
        float4 x1 = *(const float4*)(node1raw + (size_t)(pk1 & 0xFFFFF) * 32 + lane * 4);

        for (int k = 0; k < cnt; k += 2) {
            float4 xa = x0, xb = x1;
            float aa = __shfl(myex, k, 8);
            float ab = __shfl(myex, (k + 1 < cnt) ? (k + 1) : k, 8);
            if (!((k + 1) < cnt)) ab = 0.0f;

            if (k + 2 < cnt) {
                pk0 = __shfl(mypk, k + 2, 8);
                pk1 = __shfl(mypk, (k + 3 < cnt) ? (k + 3) : (k + 2), 8);
                x0 = *(const float4*)(node1raw + (size_t)(pk0 & 0xFFFFF) * 32 + lane * 4);
                x1 = *(const float4*)(node1raw + (size_t)(pk1 & 0xFFFFF) * 32 + lane * 4);
            }
            acc.x += aa * xa.x + ab * xb.x;
            acc.y += aa * xa.y + ab * xb.y;
            acc.z += aa * xa.z + ab * xb.z;
            acc.w += aa * xa.w + ab * xb.w;
        }
    }
    // combine halves (lane^8 within 16, via DPP row_ror:8)
    acc.x = xor8add(acc.x);
    acc.y = xor8add(acc.y);
    acc.z = xor8add(acc.z);
    acc.w = xor8add(acc.w);

    float inv = sinv[v];
    acc.x *= inv; acc.y *= inv; acc.z *= inv; acc.w *= inv;

    float ss = red8(n.x*n.x + n.y*n.y + n.z*n.z + n.w*n.w);
    float inv1 = inv_norm(ss);

    if (!half) {
        float4 nn = {n.x*inv1, n.y*inv1, n.z*inv1, n.w*inv1};
        *(float4*)(out + (size_t)v * 112 + 64 + lane * 4) = nn;
        float4 av = {n.x + acc.x, n.y + acc.y, n.z + acc.z, n.w + acc.w};
        float4 bv = {n.x * acc.x, n.y * acc.y, n.z * acc.z, n.w * acc.w};
        *(float4*)&A[nv][lane * 4] = av;
        *(float4*)&B[nv][lane * 4] = bv;
    }
    // no __syncthreads: writers and readers are the same wave (program order)

    int j = t & 15;
    float a1 = b1[j], a2 = b2[j];
    #pragma unroll
    for (int dd = 0; dd < 8; ++dd) {
        float4 a4 = *(const float4*)&A[nv][dd * 4];   // LDS broadcast read
        float4 b4 = *(const float4*)&B[nv][dd * 4];
        float4 wc = WtC[dd * 16 + j];
        float4 wd = WtD[dd * 16 + j];
        a1 += a4.x*wc.x + a4.y*wc.y + a4.z*wc.z + a4.w*wc.w;
        a2 += b4.x*wd.x + b4.y*wd.y + b4.z*wd.z + b4.w*wd.w;
    }
    float tot = leaky(a1) + leaky(a2);
    float s2 = red16(tot * tot);
    float inv2 = inv_norm(s2);
    out[(size_t)v * 112 + 96 + j] = tot * inv2;  // cols 96..111
}

extern "C" void kernel_launch(void* const* d_in, const int* in_sizes, int n_in,
                              void* d_out, int out_size, void* d_ws, size_t ws_size,
                              hipStream_t stream) {
    const int*   src  = (const int*)d_in[0];
    const int*   dst  = (const int*)d_in[1];
    const int*   ety  = (const int*)d_in[2];
    const float* ent  = (const float*)d_in[3];
    const float* entT = (const float*)d_in[4];
    const float* relE = (const float*)d_in[5];
    const float* relT = (const float*)d_in[6];
    const float* W1_0 = (const float*)d_in[7];
    const float* b1_0 = (const float*)d_in[8];
    const float* W2_0 = (const float*)d_in[9];
    const float* b2_0 = (const float*)d_in[10];
    const float* W1_1 = (const float*)d_in[11];
    const float* b1_1 = (const float*)d_in[12];
    const float* W2_1 = (const float*)d_in[13];
    const float* b2_1 = (const float*)d_in[14];
    float* out = (float*)d_out;

    const int E = in_sizes[0];
    const int N = in_sizes[3] / 64;
    const int nb = (N + 255) / 256;  // scan blocks (must be <= 1024)

    auto al256 = [](size_t x) { return (x + 255) & ~(size_t)255; };
    char* ws = (char*)d_ws;
    size_t offExatt = 0;
    size_t offDn    = al256(offExatt + (size_t)E * 4);
    size_t offS     = al256(offDn + (size_t)N * 8);
    size_t offRow   = al256(offS + (size_t)N * 4);
    size_t offSpk   = al256(offRow + (size_t)N * 4);
    size_t offHrp   = al256(offSpk + (size_t)E * 16);
    size_t offRp2   = al256(offHrp + (size_t)N * 16 * 4);
    size_t offPart  = al256(offRp2 + 16 * 4);
    size_t offN1    = al256(offPart + (size_t)nb * 4);
    size_t offWt    = al256(offN1 + (size_t)N * 32 * 4);
    float*  exatt    = (float*)(ws + offExatt);
    float2* dn       = (float2*)(ws + offDn);
    float*  sinv     = (float*)(ws + offS);
    int*    rowptr   = (int*)(ws + offRow);
    int4*   spk4     = (int4*)(ws + offSpk);
    float*  hrp      = (float*)(ws + offHrp);
    float*  rp2      = (float*)(ws + offRp2);
    int*    part     = (int*)(ws + offPart);
    float*  node1raw = (float*)(ws + offN1);   // [N,32]
    float4* wt       = (float4*)(ws + offWt);  // 1280 float4 transposed weights

    // ---- CSR build + per-node terms + weight transpose ----
    hipMemsetAsync(rowptr, 0, (size_t)N * 4, stream);
    int N16 = N * 16;
    int prepWork = N16 + E + N16 + 16 + 1280;
    prep<<<(prepWork + 255) / 256, 256, 0, stream>>>(
        ent, entT, dn, dst, rowptr, N16, E, relT, hrp, rp2,
        W1_0, W2_0, W1_1, W2_1, wt);
    scan_reduce<<<nb, 256, 0, stream>>>(rowptr, part, N);
    scan_part<<<1, 1024, 0, stream>>>(part, nb);
    scan_write<<<nb, 256, 0, stream>>>(rowptr, part, N);
    int blkE = (E + 255) / 256;
    scatter_edges<<<blkE, 256, 0, stream>>>(src, dst, ety, dn, hrp, rp2,
                                            rowptr, spk4, E);

    // ---- fused layer 0: attention + softmax + message + node update ----
    fused_l0<<<(N + 7) / 8, 256, 0, stream>>>(
        rowptr, spk4, ent, dn, relE, relT,
        wt, b1_0, b2_0, exatt, sinv, node1raw, out, N);

    // ---- fused layer 1: message + node update + norms ----
    fused_l1<<<(N + 15) / 16, 256, 0, stream>>>(
        rowptr, spk4, exatt, sinv, node1raw, wt,
        b1_1, b2_1, out, N);
}

// Round 14
// 203.157 us; speedup vs baseline: 1.2535x; 1.2535x over previous
//
#include <hip/hip_runtime.h>
#include <math.h>

#define EPSF 1e-12f
#define LOG2E 1.44269504f

// ---- DPP-based reductions (no DS pipe, no lane-addr calc) ----
template <int CTRL>
__device__ __forceinline__ float dppadd(float x) {
    union { float f; int i; } u, r;
    u.f = x;
    r.i = __builtin_amdgcn_update_dpp(0, u.i, CTRL, 0xF, 0xF, false);
    return x + r.f;
}
__device__ __forceinline__ float red16(float v) {
    v = dppadd<0xB1>(v); v = dppadd<0x4E>(v);
    v = dppadd<0x141>(v); v = dppadd<0x140>(v);
    return v;  // all 16 lanes hold the total
}
__device__ __forceinline__ float red8(float v) {
    v = dppadd<0xB1>(v); v = dppadd<0x4E>(v); v = dppadd<0x141>(v);
    return v;  // all 8 lanes hold the total
}
__device__ __forceinline__ float xor8add(float v) {  // combine 8-halves in 16
    return dppadd<0x128>(v);
}

// tanh(x) = 1 - 2/(e^{2x}+1) with HW exp2/rcp (exact at +/-inf limits)
__device__ __forceinline__ float fast_tanh(float x) {
    float E = __builtin_amdgcn_exp2f(x * (2.0f * LOG2E));
    return 1.0f - 2.0f * __builtin_amdgcn_rcpf(E + 1.0f);
}

// 1/max(sqrt(x), 1e-12) == rsq(max(x, 1e-24)) (monotone transform, exact)
__device__ __forceinline__ float inv_norm(float x) {
    return __builtin_amdgcn_rsqf(fmaxf(x, 1e-24f));
}

__device__ __forceinline__ float leaky(float x) {
    return x > 0.0f ? x : 0.01f * x;
}

// ---- prep, 4 segments (relT staged in LDS for the hrp computation):
// [0,N16):        dn[n] = {ent.entT, |ent|^2} AND hrp[n][0..15] = ent[n].relT[r]
//                 (16 lanes/node; lane r stores hrp[n][r] via red16 - coalesced)
// [N16,N16+E):    degree count
// [.., +16):      rp2[r] = |relT[r]|^2
// [.., +1280):    transposed-weight float4 blocks
__global__ __launch_bounds__(256) void prep(
    const float* __restrict__ ent, const float* __restrict__ entT,
    float2* __restrict__ dn, const int* __restrict__ dst,
    int* __restrict__ deg, int N16, int E,
    const float* __restrict__ relT, float* __restrict__ hrp,
    float* __restrict__ rp2,
    const float* __restrict__ W10, const float* __restrict__ W20,
    const float* __restrict__ W11, const float* __restrict__ W21,
    float4* __restrict__ wt) {
    __shared__ float rTl[16][64];
    int t = threadIdx.x;
    {   // stage relT: 256 threads = 16 rows x 16 quads
        int r = t >> 4, c = (t & 15) * 4;
        *(float4*)&rTl[r][c] = *(const float4*)(relT + r * 64 + c);
    }
    __syncthreads();

    int gid = blockIdx.x * 256 + t;
    if (gid < N16) {   // 16-lane rows never straddle (N16 mult of 256)
        int v = gid >> 4, lane = gid & 15;
        const float4 a = *(const float4*)(ent  + (size_t)v * 64 + lane * 4);
        const float4 b = *(const float4*)(entT + (size_t)v * 64 + lane * 4);
        float d  = red16(a.x*b.x + a.y*b.y + a.z*b.z + a.w*b.w);
        float n2 = red16(a.x*a.x + a.y*a.y + a.z*a.z + a.w*a.w);
        if (lane == 0) dn[v] = make_float2(d, n2);
        #pragma unroll
        for (int r = 0; r < 16; ++r) {
            const float4 w = *(const float4*)&rTl[r][lane * 4];
            float p = a.x*w.x + a.y*w.y + a.z*w.z + a.w*w.w;
            p = red16(p);
            if (lane == r) hrp[(size_t)v * 16 + r] = p;  // coalesced per group
        }
    } else if (gid < N16 + E) {
        int e = gid - N16;
        atomicAdd(&deg[dst[e]], 1);
    } else if (gid < N16 + E + 16) {
        int r = gid - N16 - E;
        const float4* w4 = (const float4*)(relT + r * 64);
        float acc = 0.0f;
        #pragma unroll
        for (int k = 0; k < 16; ++k) {
            float4 b = w4[k];
            acc += b.x*b.x + b.y*b.y + b.z*b.z + b.w*b.w;
        }
        rp2[r] = acc;
    } else {
        int w = gid - N16 - E - 16;  // 0..1279
        if (w < 512) {
            int dd = w >> 5, j = w & 31, d4 = dd * 4;
            wt[w] = make_float4(W10[(d4+0)*32+j], W10[(d4+1)*32+j],
                                W10[(d4+2)*32+j], W10[(d4+3)*32+j]);
        } else if (w < 1024) {
            int u = w - 512, dd = u >> 5, j = u & 31, d4 = dd * 4;
            wt[w] = make_float4(W20[(d4+0)*32+j], W20[(d4+1)*32+j],
                                W20[(d4+2)*32+j], W20[(d4+3)*32+j]);
        } else if (w < 1152) {
            int u = w - 1024, dd = u >> 4, j = u & 15, d4 = dd * 4;
            wt[w] = make_float4(W11[(d4+0)*16+j], W11[(d4+1)*16+j],
                                W11[(d4+2)*16+j], W11[(d4+3)*16+j]);
        } else if (w < 1280) {
            int u = w - 1152, dd = u >> 4, j = u & 15, d4 = dd * 4;
            wt[w] = make_float4(W21[(d4+0)*16+j], W21[(d4+1)*16+j],
                                W21[(d4+2)*16+j], W21[(d4+3)*16+j]);
        }
    }
}

// ---------------- CSR scan kernels ----------------

__global__ __launch_bounds__(256) void scan_reduce(
    const int* __restrict__ deg, int* __restrict__ part, int N) {
    __shared__ int sh[256];
    int t = threadIdx.x, i = blockIdx.x * 256 + t;
    sh[t] = (i < N) ? deg[i] : 0;
    __syncthreads();
    for (int off = 128; off > 0; off >>= 1) {
        if (t < off) sh[t] += sh[t + off];
        __syncthreads();
    }
    if (t == 0) part[blockIdx.x] = sh[0];
}

__global__ __launch_bounds__(1024) void scan_part(int* __restrict__ part, int nb) {
    __shared__ int sh[1024];
    int t = threadIdx.x;
    int x = (t < nb) ? part[t] : 0;
    sh[t] = x;
    __syncthreads();
    for (int off = 1; off < 1024; off <<= 1) {
        int y = (t >= off) ? sh[t - off] : 0;
        __syncthreads();
        sh[t] += y;
        __syncthreads();
    }
    if (t < nb) part[t] = sh[t] - x;  // exclusive
}

__global__ __launch_bounds__(256) void scan_write(
    int* __restrict__ rowptr, const int* __restrict__ part, int N) {
    __shared__ int sh[256];
    int t = threadIdx.x, i = blockIdx.x * 256 + t;
    int x = (i < N) ? rowptr[i] : 0;
    sh[t] = x;
    __syncthreads();
    for (int off = 1; off < 256; off <<= 1) {
        int y = (t >= off) ? sh[t - off] : 0;
        __syncthreads();
        sh[t] += y;
        __syncthreads();
    }
    if (i < N) rowptr[i] = part[blockIdx.x] + sh[t] - x;  // exclusive scan
}

// After this, rowptr[v] = end(v); start(v) = (v ? rowptr[v-1] : 0).
// Slot payload int4: { src|ety<<20, dot[src], it, ih } — the two edge
// normalizers are computed HERE from precomputed quadratic-form terms.
__global__ __launch_bounds__(256) void scatter_edges(
    const int* __restrict__ src, const int* __restrict__ dst,
    const int* __restrict__ ety, const float2* __restrict__ dn,
    const float* __restrict__ hrp, const float* __restrict__ rp2,
    int* __restrict__ rowptr, int4* __restrict__ spk4, int E) {
    int e = blockIdx.x * 256 + threadIdx.x;
    if (e < E) {
        int sv = src[e], dv = dst[e], rv = ety[e];
        float2 dns = dn[sv], dnd = dn[dv];
        float hs = hrp[(size_t)sv * 16 + rv], hd = hrp[(size_t)dv * 16 + rv];
        float r2 = rp2[rv];
        float sdt = dns.x, dh = dnd.x;
        // |te + sdt*rp|^2 and |he + dh*rp|^2 via quadratic expansion
        float sst = dns.y + 2.0f * sdt * hs + sdt * sdt * r2;
        float ssh = dnd.y + 2.0f * dh  * hd + dh  * dh  * r2;
        float it = inv_norm(sst);
        float ih = inv_norm(ssh);
        int slot = atomicAdd(&rowptr[dv], 1);
        spk4[slot] = make_int4(sv | (rv << 20), __float_as_int(sdt),
                               __float_as_int(it), __float_as_int(ih));
    }
}

// ------------- fused layer-0: att + softmax + message + bi-layer GEMV -------
// 32 lanes per dst node (8 nodes / 256-thread block): two 16-lane halves each
// walk half the node's edge list with a dual-edge pipeline + next-pair
// prefetch. Normalizers it/ih arrive precomputed in the payload — no
// per-edge norm reductions remain; only the attention dot red16.
__global__ __launch_bounds__(256) void fused_l0(
    const int* __restrict__ rowptr, const int4* __restrict__ spk4,
    const float* __restrict__ ent, const float2* __restrict__ dn,
    const float* __restrict__ relE, const float* __restrict__ relT,
    const float4* __restrict__ wt,
    const float* __restrict__ b1, const float* __restrict__ b2,
    float* __restrict__ exatt, float* __restrict__ sinv,
    float* __restrict__ node1raw, float* __restrict__ out, int N) {
    __shared__ float  al[8][64];
    __shared__ float  bl[8][64];
    __shared__ float  rT[16][64];    // rel tables (16 rels x 64)
    __shared__ float  rE[16][64];
    __shared__ float4 WtA[512];      // W1^T (pre-transposed in prep)
    __shared__ float4 WtB[512];
    int t = threadIdx.x;

    {   // stage rel tables + weights (pure coalesced float4 copies)
        int r = t >> 4, c = (t & 15) * 4;
        *(float4*)&rT[r][c] = *(const float4*)(relT + r * 64 + c);
        *(float4*)&rE[r][c] = *(const float4*)(relE + r * 64 + c);
        WtA[t]       = wt[t];
        WtA[t + 256] = wt[t + 256];
        WtB[t]       = wt[512 + t];
        WtB[t + 256] = wt[768 + t];
    }
    __syncthreads();  // the only block barrier

    int nv = t >> 5, half = (t >> 4) & 1, lane = t & 15;
    int v = blockIdx.x * 8 + nv;
    if (v >= N) return;

    int s = v ? rowptr[v - 1] : 0;
    int epos = rowptr[v];
    int deg = epos - s;
    int mid = s + ((deg + 1) >> 1);
    int hs   = half ? mid  : s;
    int hend = half ? epos : mid;

    const float4 he = *(const float4*)(ent + (size_t)v * 64 + lane * 4);
    float dh = dn[v].x;

    float4 macc = {0.f, 0.f, 0.f, 0.f};
    float sumex = 0.0f;

    for (int base = hs; base < hend; base += 16) {
        int rem = hend - base;
        int cnt = rem < 16 ? rem : 16;
        int4 ms = spk4[base + (lane < rem ? lane : rem - 1)];  // coalesced 16B
        float myex = 0.0f;

        int e1i = cnt > 1 ? 1 : 0;
        int   pk0 = __shfl(ms.x, 0, 16);
        int   pk1 = __shfl(ms.x, e1i, 16);
        float sd0 = __int_as_float(__shfl(ms.y, 0, 16));
        float sd1 = __int_as_float(__shfl(ms.y, e1i, 16));
        float it0 = __int_as_float(__shfl(ms.z, 0, 16));
        float it1 = __int_as_float(__shfl(ms.z, e1i, 16));
        float ih0 = __int_as_float(__shfl(ms.w, 0, 16));
        float ih1 = __int_as_float(__shfl(ms.w, e1i, 16));
        float4 te0 = *(const float4*)(ent + (size_t)(pk0 & 0xFFFFF) * 64 + lane * 4);
        float4 te1 = *(const float4*)(ent + (size_t)(pk1 & 0xFFFFF) * 64 + lane * 4);

        for (int k = 0; k < cnt; k += 2) {
            float4 ta = te0, tb = te1;
            float  sa = sd0, sb = sd1;
            float ita = it0, itb = it1, iha = ih0, ihb = ih1;
            int rva = (pk0 >> 20) & 15;
            int rvb = (pk1 >> 20) & 15;
            bool hasb = (k + 1) < cnt;

            if (k + 2 < cnt) {  // prefetch next pair while computing this one
                int i2 = k + 2, i3 = (k + 3 < cnt) ? (k + 3) : (k + 2);
                pk0 = __shfl(ms.x, i2, 16);
                pk1 = __shfl(ms.x, i3, 16);
                sd0 = __int_as_float(__shfl(ms.y, i2, 16));
                sd1 = __int_as_float(__shfl(ms.y, i3, 16));
                it0 = __int_as_float(__shfl(ms.z, i2, 16));
                it1 = __int_as_float(__shfl(ms.z, i3, 16));
                ih0 = __int_as_float(__shfl(ms.w, i2, 16));
                ih1 = __int_as_float(__shfl(ms.w, i3, 16));
                te0 = *(const float4*)(ent + (size_t)(pk0 & 0xFFFFF) * 64 + lane * 4);
                te1 = *(const float4*)(ent + (size_t)(pk1 & 0xFFFFF) * 64 + lane * 4);
            }

            const float4 rpa = *(const float4*)&rT[rva][lane * 4];
            const float4 rea = *(const float4*)&rE[rva][lane * 4];
            const float4 rpb = *(const float4*)&rT[rvb][lane * 4];
            const float4 reb = *(const float4*)&rE[rvb][lane * 4];

            float4 mta, mha, mtb, mhb;
            mta.x = ta.x + sa * rpa.x; mta.y = ta.y + sa * rpa.y;
            mta.z = ta.z + sa * rpa.z; mta.w = ta.w + sa * rpa.w;
            mha.x = he.x + dh * rpa.x; mha.y = he.y + dh * rpa.y;
            mha.z = he.z + dh * rpa.z; mha.w = he.w + dh * rpa.w;
            mtb.x = tb.x + sb * rpb.x; mtb.y = tb.y + sb * rpb.y;
            mtb.z = tb.z + sb * rpb.z; mtb.w = tb.w + sb * rpb.w;
            mhb.x = he.x + dh * rpb.x; mhb.y = he.y + dh * rpb.y;
            mhb.z = he.z + dh * rpb.z; mhb.w = he.w + dh * rpb.w;

            float txa = fast_tanh(mha.x * iha + rea.x);
            float tya = fast_tanh(mha.y * iha + rea.y);
            float tza = fast_tanh(mha.z * iha + rea.z);
            float twa = fast_tanh(mha.w * iha + rea.w);
            float txb = fast_tanh(mhb.x * ihb + reb.x);
            float tyb = fast_tanh(mhb.y * ihb + reb.y);
            float tzb = fast_tanh(mhb.z * ihb + reb.z);
            float twb = fast_tanh(mhb.w * ihb + reb.w);

            float atta = ita * red16(mta.x*txa + mta.y*tya + mta.z*tza + mta.w*twa);
            float attb = itb * red16(mtb.x*txb + mtb.y*tyb + mtb.z*tzb + mtb.w*twb);

            // softmax shift-invariant; |att| <= 8 so exp is safe without max-sub
            float exa  = __builtin_amdgcn_exp2f(atta * LOG2E);
            float exbR = __builtin_amdgcn_exp2f(attb * LOG2E);
            float exb  = hasb ? exbR : 0.0f;

            // lane k captures its edge's raw ex; stored coalesced per chunk
            myex = (lane == k) ? exa : myex;
            myex = (lane == k + 1) ? exbR : myex;

            sumex += exa + exb;
            macc.x += exa * ta.x + exb * tb.x;
            macc.y += exa * ta.y + exb * tb.y;
            macc.z += exa * ta.z + exb * tb.z;
            macc.w += exa * ta.w + exb * tb.w;
        }
        if (lane < cnt) exatt[base + lane] = myex;
    }

    // combine the two halves of this node (width-32 xor-by-16)
    sumex  += __shfl_xor(sumex,  16, 32);
    macc.x += __shfl_xor(macc.x, 16, 32);
    macc.y += __shfl_xor(macc.y, 16, 32);
    macc.z += __shfl_xor(macc.z, 16, 32);
    macc.w += __shfl_xor(macc.w, 16, 32);

    float inv = 1.0f / fmaxf(sumex, EPSF);
    if ((t & 31) == 0) sinv[v] = inv;
    macc.x *= inv; macc.y *= inv; macc.z *= inv; macc.w *= inv;

    if (!half) {
        // out cols 0..63 = ent_embed
        *(float4*)(out + (size_t)v * 112 + lane * 4) = he;
        float4 av, bv;
        av.x = he.x + macc.x; av.y = he.y + macc.y;
        av.z = he.z + macc.z; av.w = he.w + macc.w;
        bv.x = he.x * macc.x; bv.y = he.y * macc.y;
        bv.z = he.z * macc.z; bv.w = he.w * macc.w;
        *(float4*)&al[nv][lane * 4] = av;
        *(float4*)&bl[nv][lane * 4] = bv;
    }
    // no __syncthreads: writers and readers are the same wave (program order)

    int j = t & 31;
    float acc1 = b1[j], acc2 = b2[j];
    #pragma unroll
    for (int dd = 0; dd < 16; ++dd) {
        float4 a4 = *(const float4*)&al[nv][dd * 4];   // LDS broadcast read
        float4 b4 = *(const float4*)&bl[nv][dd * 4];
        float4 wa = WtA[dd * 32 + j];                  // coalesced b128
        float4 wb = WtB[dd * 32 + j];
        acc1 += a4.x*wa.x + a4.y*wa.y + a4.z*wa.z + a4.w*wa.w;
        acc2 += b4.x*wb.x + b4.y*wb.y + b4.z*wb.z + b4.w*wb.w;
    }
    node1raw[(size_t)v * 32 + j] = leaky(acc1) + leaky(acc2);
}

// ------------- fused layer-1: message gather + bi-layer GEMV + norms --------
// 16 lanes per node (16 nodes / block): two 8-lane halves, dual-edge pipeline.
__global__ __launch_bounds__(256) void fused_l1(
    const int* __restrict__ rowptr, const int4* __restrict__ spk4,
    const float* __restrict__ exatt, const float* __restrict__ sinv,
    const float* __restrict__ node1raw, const float4* __restrict__ wt,
    const float* __restrict__ b1, const float* __restrict__ b2,
    float* __restrict__ out, int N) {
    __shared__ float  A[16][32];
    __shared__ float  B[16][32];
    __shared__ float4 WtC[128];  // W1^T (pre-transposed in prep)
    __shared__ float4 WtD[128];
    int t = threadIdx.x;

    {   // stage weights (pure coalesced float4 copies)
        if (t < 128) WtC[t] = wt[1024 + t];
        else WtD[t - 128] = wt[1024 + t];
    }
    __syncthreads();

    int nv = t >> 4, half = (t >> 3) & 1, lane = t & 7;
    int v = blockIdx.x * 16 + nv;
    if (v >= N) return;

    int s = v ? rowptr[v - 1] : 0;
    int epos = rowptr[v];
    int deg = epos - s;
    int mid = s + ((deg + 1) >> 1);
    int hs   = half ? mid  : s;
    int hend = half ? epos : mid;

    float4 n = *(const float4*)(node1raw + (size_t)v * 32 + lane * 4);
    float4 acc = {0.f, 0.f, 0.f, 0.f};

    for (int base = hs; base < hend; base += 8) {
        int rem = hend - base;
        int cnt = rem < 8 ? rem : 8;
        int idx = base + (lane < rem ? lane : rem - 1);
        int   mypk = spk4[idx].x;
        float myex = exatt[idx];

        int pk0 = __shfl(mypk, 0, 8);
        int pk1 = __shfl(mypk, cnt > 1 ? 1 : 0, 8);
        float4 x0 = *(const float4*)(node1raw + (size_t)(pk0 & 0xFFFFF) * 32 + lane * 4);
        float4 x1 = *(const float4*)(node1raw + (size_t)(pk1 & 0xFFFFF) * 32 + lane * 4);

        for (int k = 0; k < cnt; k += 2) {
            float4 xa = x0, xb = x1;
            float aa = __shfl(myex, k, 8);
            float ab = __shfl(myex, (k + 1 < cnt) ? (k + 1) : k, 8);
            if (!((k + 1) < cnt)) ab = 0.0f;

            if (k + 2 < cnt) {
                pk0 = __shfl(mypk, k + 2, 8);
                pk1 = __shfl(mypk, (k + 3 < cnt) ? (k + 3) : (k + 2), 8);
                x0 = *(const float4*)(node1raw + (size_t)(pk0 & 0xFFFFF) * 32 + lane * 4);
                x1 = *(const float4*)(node1raw + (size_t)(pk1 & 0xFFFFF) * 32 + lane * 4);
            }
            acc.x += aa * xa.x + ab * xb.x;
            acc.y += aa * xa.y + ab * xb.y;
            acc.z += aa * xa.z + ab * xb.z;
            acc.w += aa * xa.w + ab * xb.w;
        }
    }
    // combine halves (lane^8 within 16, via DPP row_ror:8)
    acc.x = xor8add(acc.x);
    acc.y = xor8add(acc.y);
    acc.z = xor8add(acc.z);
    acc.w = xor8add(acc.w);

    float inv = sinv[v];
    acc.x *= inv; acc.y *= inv; acc.z *= inv; acc.w *= inv;

    float ss = red8(n.x*n.x + n.y*n.y + n.z*n.z + n.w*n.w);
    float inv1 = inv_norm(ss);

    if (!half) {
        float4 nn = {n.x*inv1, n.y*inv1, n.z*inv1, n.w*inv1};
        *(float4*)(out + (size_t)v * 112 + 64 + lane * 4) = nn;
        float4 av = {n.x + acc.x, n.y + acc.y, n.z + acc.z, n.w + acc.w};
        float4 bv = {n.x * acc.x, n.y * acc.y, n.z * acc.z, n.w * acc.w};
        *(float4*)&A[nv][lane * 4] = av;
        *(float4*)&B[nv][lane * 4] = bv;
    }
    // no __syncthreads: writers and readers are the same wave (program order)

    int j = t & 15;
    float a1 = b1[j], a2 = b2[j];
    #pragma unroll
    for (int dd = 0; dd < 8; ++dd) {
        float4 a4 = *(const float4*)&A[nv][dd * 4];   // LDS broadcast read
        float4 b4 = *(const float4*)&B[nv][dd * 4];
        float4 wc = WtC[dd * 16 + j];
        float4 wd = WtD[dd * 16 + j];
        a1 += a4.x*wc.x + a4.y*wc.y + a4.z*wc.z + a4.w*wc.w;
        a2 += b4.x*wd.x + b4.y*wd.y + b4.z*wd.z + b4.w*wd.w;
    }
    float tot = leaky(a1) + leaky(a2);
    float s2 = red16(tot * tot);
    float inv2 = inv_norm(s2);
    out[(size_t)v * 112 + 96 + j] = tot * inv2;  // cols 96..111
}

extern "C" void kernel_launch(void* const* d_in, const int* in_sizes, int n_in,
                              void* d_out, int out_size, void* d_ws, size_t ws_size,
                              hipStream_t stream) {
    const int*   src  = (const int*)d_in[0];
    const int*   dst  = (const int*)d_in[1];
    const int*   ety  = (const int*)d_in[2];
    const float* ent  = (const float*)d_in[3];
    const float* entT = (const float*)d_in[4];
    const float* relE = (const float*)d_in[5];
    const float* relT = (const float*)d_in[6];
    const float* W1_0 = (const float*)d_in[7];
    const float* b1_0 = (const float*)d_in[8];
    const float* W2_0 = (const float*)d_in[9];
    const float* b2_0 = (const float*)d_in[10];
    const float* W1_1 = (const float*)d_in[11];
    const float* b1_1 = (const float*)d_in[12];
    const float* W2_1 = (const float*)d_in[13];
    const float* b2_1 = (const float*)d_in[14];
    float* out = (float*)d_out;

    const int E = in_sizes[0];
    const int N = in_sizes[3] / 64;
    const int nb = (N + 255) / 256;  // scan blocks (must be <= 1024)

    auto al256 = [](size_t x) { return (x + 255) & ~(size_t)255; };
    char* ws = (char*)d_ws;
    size_t offExatt = 0;
    size_t offDn    = al256(offExatt + (size_t)E * 4);
    size_t offS     = al256(offDn + (size_t)N * 8);
    size_t offRow   = al256(offS + (size_t)N * 4);
    size_t offSpk   = al256(offRow + (size_t)N * 4);
    size_t offHrp   = al256(offSpk + (size_t)E * 16);
    size_t offRp2   = al256(offHrp + (size_t)N * 16 * 4);
    size_t offPart  = al256(offRp2 + 16 * 4);
    size_t offN1    = al256(offPart + (size_t)nb * 4);
    size_t offWt    = al256(offN1 + (size_t)N * 32 * 4);
    float*  exatt    = (float*)(ws + offExatt);
    float2* dn       = (float2*)(ws + offDn);
    float*  sinv     = (float*)(ws + offS);
    int*    rowptr   = (int*)(ws + offRow);
    int4*   spk4     = (int4*)(ws + offSpk);
    float*  hrp      = (float*)(ws + offHrp);
    float*  rp2      = (float*)(ws + offRp2);
    int*    part     = (int*)(ws + offPart);
    float*  node1raw = (float*)(ws + offN1);   // [N,32]
    float4* wt       = (float4*)(ws + offWt);  // 1280 float4 transposed weights

    // ---- CSR build + per-node terms + weight transpose ----
    hipMemsetAsync(rowptr, 0, (size_t)N * 4, stream);
    int N16 = N * 16;
    int prepWork = N16 + E + 16 + 1280;
    prep<<<(prepWork + 255) / 256, 256, 0, stream>>>(
        ent, entT, dn, dst, rowptr, N16, E, relT, hrp, rp2,
        W1_0, W2_0, W1_1, W2_1, wt);
    scan_reduce<<<nb, 256, 0, stream>>>(rowptr, part, N);
    scan_part<<<1, 1024, 0, stream>>>(part, nb);
    scan_write<<<nb, 256, 0, stream>>>(rowptr, part, N);
    int blkE = (E + 255) / 256;
    scatter_edges<<<blkE, 256, 0, stream>>>(src, dst, ety, dn, hrp, rp2,
                                            rowptr, spk4, E);

    // ---- fused layer 0: attention + softmax + message + node update ----
    fused_l0<<<(N + 7) / 8, 256, 0, stream>>>(
        rowptr, spk4, ent, dn, relE, relT,
        wt, b1_0, b2_0, exatt, sinv, node1raw, out, N);

    // ---- fused layer 1: message + node update + norms ----
    fused_l1<<<(N + 15) / 16, 256, 0, stream>>>(
        rowptr, spk4, exatt, sinv, node1raw, wt,
        b1_1, b2_1, out, N);
}